// Round 5
// baseline (398.610 us; speedup 1.0000x reference)
//
#include <hip/hip_runtime.h>

#define B_DIM   256
#define T_STEPS 2000
#define F_DIM   128
#define TILE    256
#define NT      8     // 7 tiles of 256 + tail of 208
#define RING    8     // LDS ring depth (tiles); 8 KB
#define DSCAN   2     // consumer lags its own production by 2 tiles

// Fused Dense(1) + LIF. One block per batch element (256 blocks, 1024 thr =
// 16 waves, 1 block/CU). Producer-consumer: all 16 waves produce cur-tiles
// into an 8-deep LDS ring, self-paced via LDS flags (no __syncthreads in the
// steady state) so HBM loads are never gated by the serial scan. Wave 0
// additionally consumes (scans) tiles, lagging DSCAN behind.
__global__ __launch_bounds__(1024) void lif_fused3(
    const float* __restrict__ x, const float* __restrict__ W,
    const float* __restrict__ bias, float* __restrict__ out, int B) {
  const float BETA = 0.8807970779778823f;  // sigmoid(2.0)

  __shared__ __align__(16) float ring[RING][TILE];
  __shared__ int arr[RING];   // per-slot producer-arrival count (0..16)
  __shared__ int done;        // highest tile index fully scanned

  const int tid  = threadIdx.x;
  const int lane = tid & 63;
  const int wave = tid >> 6;    // 0..15
  const int sub  = lane & 15;   // float4 index within a row half
  const int grp  = lane >> 4;   // row within this wave's 4-row group
  const int b    = blockIdx.x;

  if (tid < RING) arr[tid] = 0;
  if (tid == 0)   done = -1;
  __syncthreads();

  const float4 wlo = ((const float4*)W)[sub];
  const float4 whi = ((const float4*)W)[sub + 16];
  const float  bs  = bias[0];
  const float* xb  = x + (size_t)b * T_STEPS * F_DIM;
  float* outb = out + (size_t)b * T_STEPS;

  float v = 0.0f;

  auto tileLen = [&](int c) {
    const int t0 = c * TILE;
    return (T_STEPS - t0 < TILE) ? (T_STEPS - t0) : TILE;
  };

  // ---- producer: load+reduce this wave's 16 rows of tile k into ring slot
  auto produce = [&](int k) {
    const int s   = k & (RING - 1);
    const int t0  = k * TILE;
    const int len = tileLen(k);
    // flow control: slot s last held tile k-RING; wait until it's scanned
    while (__hip_atomic_load(&done, __ATOMIC_ACQUIRE,
                             __HIP_MEMORY_SCOPE_WORKGROUP) < k - RING)
      __builtin_amdgcn_s_sleep(1);

    float4 xl[4], xh[4];
#pragma unroll
    for (int q = 0; q < 4; ++q) {
      const int tl = wave * 16 + q * 4;      // wave-uniform guard
      if (tl < len) {
        const float4* row = (const float4*)(xb + (size_t)(t0 + tl + grp) * F_DIM);
        xl[q] = row[sub];
        xh[q] = row[sub + 16];
      }
    }
    float* dst = ring[s];
#pragma unroll
    for (int q = 0; q < 4; ++q) {
      const int tl = wave * 16 + q * 4;
      if (tl < len) {
        // --- bit-exact reduction order (absmax 0.0 x4 rounds) — do not reorder
        float pl = xl[q].x * wlo.x;
        pl = fmaf(xl[q].y, wlo.y, pl);
        pl = fmaf(xl[q].z, wlo.z, pl);
        pl = fmaf(xl[q].w, wlo.w, pl);
        float ph = xh[q].x * whi.x;
        ph = fmaf(xh[q].y, whi.y, ph);
        ph = fmaf(xh[q].z, whi.z, ph);
        ph = fmaf(xh[q].w, whi.w, ph);
        float sum = pl + ph;                 // == p + shfl_xor(p,16)
        sum += __shfl_xor(sum, 8, 64);
        sum += __shfl_xor(sum, 4, 64);
        sum += __shfl_xor(sum, 2, 64);
        sum += __shfl_xor(sum, 1, 64);
        if (sub == 0) dst[tl + grp] = sum + bs;
      }
    }
    __threadfence_block();                   // LDS writes visible before flag
    if (lane == 0) atomicAdd(&arr[s], 1);    // one arrival per wave
  };

  // ---- consumer (wave 0 only): scan tile k from its ring slot
  auto consume = [&](int k) {
    const int s   = k & (RING - 1);
    const int t0  = k * TILE;
    const int len = tileLen(k);              // 256 or 208
    while (__hip_atomic_load(&arr[s], __ATOMIC_ACQUIRE,
                             __HIP_MEMORY_SCOPE_WORKGROUP) != 16)
      __builtin_amdgcn_s_sleep(1);

    const float* cb = ring[s];
    const int    ng = len >> 3;              // groups of 8 (32 or 26, even)
    float sreg = 0.0f;

    auto step = [&](float cvv, int tloc) {
      const float vp   = __fadd_rn(__fmul_rn(BETA, v), cvv);
      const bool  fire = (vp >= 1.0f);           // == (vp - VTH >= 0)
      v = fire ? __fsub_rn(vp, 1.0f) : vp;       // subtraction reset
      const float sv = fire ? 1.0f : 0.0f;
      if ((tloc & 63) == lane) sreg = sv;        // lane owns t&63
    };

    float4 A0 = *(const float4*)&cb[0];
    float4 A1 = *(const float4*)&cb[4];
    for (int gg = 0; gg < ng; gg += 2) {
      float4 Bq0 = *(const float4*)&cb[(gg + 1) * 8];
      float4 Bq1 = *(const float4*)&cb[(gg + 1) * 8 + 4];
      step(A0.x, gg * 8 + 0); step(A0.y, gg * 8 + 1);
      step(A0.z, gg * 8 + 2); step(A0.w, gg * 8 + 3);
      step(A1.x, gg * 8 + 4); step(A1.y, gg * 8 + 5);
      step(A1.z, gg * 8 + 6); step(A1.w, gg * 8 + 7);
      if (gg + 2 < ng) {
        A0 = *(const float4*)&cb[(gg + 2) * 8];
        A1 = *(const float4*)&cb[(gg + 2) * 8 + 4];
      }
      const int tb = (gg + 1) * 8;
      step(Bq0.x, tb + 0); step(Bq0.y, tb + 1);
      step(Bq0.z, tb + 2); step(Bq0.w, tb + 3);
      step(Bq1.x, tb + 4); step(Bq1.y, tb + 5);
      step(Bq1.z, tb + 6); step(Bq1.w, tb + 7);
      if (((gg + 1) & 7) == 7) {                 // end of a 64-step round
        const int tend = tb + 7;                 // tend & 63 == 63
        outb[t0 + (tend - 63) + lane] = sreg;    // coalesced 256B store
      }
    }
    const int rem = len & 63;                    // 0 or 16 (tail tile)
    if (rem && lane < rem)
      outb[t0 + (len & ~63) + lane] = sreg;

    __threadfence_block();                       // reads done before reuse
    if (lane == 0) {
      __hip_atomic_store(&arr[s], 0, __ATOMIC_RELAXED,
                         __HIP_MEMORY_SCOPE_WORKGROUP);
      __threadfence_block();
      __hip_atomic_store(&done, k, __ATOMIC_RELEASE,
                         __HIP_MEMORY_SCOPE_WORKGROUP);
    }
  };

  for (int k = 0; k < NT; ++k) {
    produce(k);
    if (wave == 0 && k >= DSCAN) consume(k - DSCAN);
  }
  if (wave == 0) {
    for (int k = NT - DSCAN; k < NT; ++k) consume(k);
  }
  __syncthreads();

  if (tid == 0) out[(size_t)B_DIM * T_STEPS + b] = v;  // final Vmem
}

extern "C" void kernel_launch(void* const* d_in, const int* in_sizes, int n_in,
                              void* d_out, int out_size, void* d_ws, size_t ws_size,
                              hipStream_t stream) {
  const float* x    = (const float*)d_in[0];
  const float* W    = (const float*)d_in[1];
  const float* bias = (const float*)d_in[2];
  float* out = (float*)d_out;
  const int B = in_sizes[0] / (T_STEPS * F_DIM);  // 256
  lif_fused3<<<dim3(B), dim3(1024), 0, stream>>>(x, W, bias, out, B);
}